// Round 9
// baseline (413.882 us; speedup 1.0000x reference)
//
#include <hip/hip_runtime.h>
#include <stdint.h>

// Problem: B=1,000,000 rows; IN=64, H=128, OUT=2, 3 heads, per-row routing u in [0,3).
// out[b,:] = Wb[u[b]] @ relu(W1 @ x[b] + b1) + bb[u[b]]
//
// Roofline: mandatory HBM = x(256MB) + u(4MB) + out(8MB) ~ 268MB -> ~43us @ 6.3TB/s.
//
// Journal:
//  R2:  99us. LDS-W1, VGPR=96, no spill. Latency-bound (no overlap within wave).
//  R3: 135us. Reg-prefetch + forced 64-VGPR cap -> partial spill + half-empty machine.
//  R4: 343us. launch_bounds(256,8) -> VGPR 32 -> 225MB spill. Never force-shrink regs.
//  R5: 190us. waves_per_eu(4,4) -> still 64 VGPR, 71MB spill. Attributes don't help.
//  R6:  61us. Per-wave LDS ring + global_load_lds: in-flight bytes live in the vmcnt
//       queue, not VGPRs. WIN.
//  R7:  53us. Pair-shared compute (W1 frags once/pair), 1-ahead restage. ~5.0 TB/s eff.
//  R8:  56us. Quad slots halved waves/CU (12->6): concurrency beats wait-distance.
//       FALSIFIED latency-exposure theory; R7 is the LDS-budget local optimum.
//  R9 (this): R7 body + DYNAMIC pair scheduling (atomicAdd counter in d_ws, zeroed by
//       hipMemsetAsync each launch). Static 10-vs-11-pair quantization (~8% tail ~4us)
//       -> <=1 pair spread. Next-index grabbed one iteration ahead (atomic RTT hidden
//       under compute). Clamped restage -> skip-branch (saves 25MB dead fetch).

typedef float f32x4 __attribute__((ext_vector_type(4)));
typedef int   i32x4 __attribute__((ext_vector_type(4)));
typedef short short8 __attribute__((ext_vector_type(8)));
typedef __bf16 bf16x8 __attribute__((ext_vector_type(8)));

#define GLOBAL_AS __attribute__((address_space(1)))
#define LDS_AS    __attribute__((address_space(3)))

static __device__ __forceinline__ f32x4 mfma16(bf16x8 a, bf16x8 b, f32x4 c) {
    return __builtin_amdgcn_mfma_f32_16x16x32_bf16(a, b, c, 0, 0, 0);
}

// MFMA k-packing: any bijection (gamma=lane>>4, j)->k works if A and B use the same one.
// Trunk (K=32 step s): k = 32s + 8g + j. D: col=lane&15=batch row, row = h-dim 16t+4g+r.
// Head: A2 row = batch row (matches trunk D -> zero cross-lane movement); k-bijection
//   n = 32s + 16*(j>>2) + 4g + (j&3) = exactly the h-dims this lane holds.
//   D2: col=lane&15 = head*2+out combo (<6), row -> batch row base+4g+r.
__global__ __launch_bounds__(256) void coil_fused(
    const float* __restrict__ x,
    const int*   __restrict__ u,    // routing ids, int32 on device
    const float* __restrict__ W1,   // [128][64]
    const float* __restrict__ b1,   // [128]
    const float* __restrict__ Wb,   // [3][2][128]
    const float* __restrict__ bb,   // [3][2]
    float* __restrict__ out,        // [B][2]
    unsigned int* __restrict__ cnt, // dynamic pair counter (d_ws, zeroed per launch)
    int nPairs)
{
    __shared__ short w1s[128 * 64];   // 16 KB: W1 as bf16, XOR-swizzled rows
    __shared__ float b1s[128];
    __shared__ float xsl[4][2048];    // 32 KB: per-wave pair slot (8KB each)

    const int tid  = threadIdx.x;
    const int lane = tid & 63;
    const int c    = lane & 15;       // MFMA "parallel" index
    const int g    = lane >> 4;       // k-group gamma
    const int wsl  = tid >> 6;        // wave slot within block

    // ---- stage W1 into LDS as bf16, swizzled: phys = logical ^ ((row&7)<<4) ----
    for (int qq = tid; qq < 1024; qq += 256) {
        int row = qq >> 3;
        const float* src = W1 + row * 64 + (qq & 7) * 8;
        short8 v;
        #pragma unroll
        for (int j = 0; j < 8; ++j) v[j] = __builtin_bit_cast(short, (__bf16)src[j]);
        int phys = (qq * 16) ^ ((row & 7) << 4);
        *reinterpret_cast<short8*>(reinterpret_cast<char*>(w1s) + phys) = v;
    }
    if (tid < 128) b1s[tid] = b1[tid];

    // ---- loop-invariant head-weight fragments (16 VGPR) + head bias ----
    const int ko = c;                  // combo = head*2 + out_pos; valid if < 6
    const bool kvalid = (ko < 6);
    bf16x8 B2[4];
    #pragma unroll
    for (int s = 0; s < 4; ++s) {
        #pragma unroll
        for (int j = 0; j < 8; ++j) {
            int n = 32 * s + ((j >> 2) << 4) + 4 * g + (j & 3);
            B2[s][j] = kvalid ? (__bf16)Wb[ko * 128 + n] : (__bf16)0.0f;
        }
    }
    const float bbr = kvalid ? bb[ko] : 0.0f;
    const int khead = ko >> 1, opos = ko & 1;

    __syncthreads();   // only barrier in the kernel

    // ---- per-lane pre-swizzled GLOBAL offsets for x staging (8 chunks of 1KB) ----
    // LDS phys byte P = i*1024 + lane*16 holds x logical byte P ^ (((P>>8)&7)<<4)
    // (XOR touches bits 4-6 only; row bits unaffected).
    int xoff[8];
    #pragma unroll
    for (int i = 0; i < 8; ++i) {
        int pb = i * 1024 + lane * 16;
        xoff[i] = pb ^ (((pb >> 8) & 7) << 4);
    }

    // ---- x read offsets within the slot (bytes), swizzle-corrected; tile B = +4096 ----
    const int sw  = (c & 7) << 4;
    const int r00 = (c * 256 + g * 32 +   0) ^ sw;   // s=0, j=0..3
    const int r01 = (c * 256 + g * 32 +  16) ^ sw;   // s=0, j=4..7
    const int r10 = (c * 256 + g * 32 + 128) ^ sw;   // s=1, j=0..3
    const int r11 = (c * 256 + g * 32 + 144) ^ sw;   // s=1, j=4..7

    const char* xb8 = reinterpret_cast<const char*>(x);
    const char* w1b = reinterpret_cast<const char*>(w1s);
    float* slot = &xsl[wsl][0];
    LDS_AS char* dst = (LDS_AS char*)slot;
    const char* sb = reinterpret_cast<const char*>(slot);

    // ---- dynamic pair grabber: one atomic per pair, wave-uniform via shfl ----
    auto grab = [&]() -> int {
        int v = 0;
        if (lane == 0) v = (int)atomicAdd(cnt, 1u);
        return __shfl(v, 0);
    };

    auto stage = [&](int pairIdx, i32x4& uvA, i32x4& uvB) {
        const int t0 = pairIdx * 2;
        uvA = *reinterpret_cast<const i32x4*>(u + t0 * 16 + 4 * g);
        uvB = *reinterpret_cast<const i32x4*>(u + t0 * 16 + 16 + 4 * g);
        const char* src = xb8 + (size_t)t0 * 4096;
        #pragma unroll
        for (int i = 0; i < 8; ++i)
            __builtin_amdgcn_global_load_lds((const GLOBAL_AS void*)(src + xoff[i]),
                                             (LDS_AS void*)(dst + i * 1024), 16, 0, 0);
    };

    int p = grab();
    if (p >= nPairs) return;

    i32x4 uvA, uvB, nuvA, nuvB;
    stage(p, uvA, uvB);
    int np = grab();                       // prefetched next index

    while (true) {
        // ---- read both tiles' x fragments (waits on this slot's in-flight DMA) ----
        f32x4 xaA = *reinterpret_cast<const f32x4*>(sb + r00);
        f32x4 xbA = *reinterpret_cast<const f32x4*>(sb + r01);
        f32x4 xcA = *reinterpret_cast<const f32x4*>(sb + r10);
        f32x4 xdA = *reinterpret_cast<const f32x4*>(sb + r11);
        f32x4 xaB = *reinterpret_cast<const f32x4*>(sb + 4096 + r00);
        f32x4 xbB = *reinterpret_cast<const f32x4*>(sb + 4096 + r01);
        f32x4 xcB = *reinterpret_cast<const f32x4*>(sb + 4096 + r10);
        f32x4 xdB = *reinterpret_cast<const f32x4*>(sb + 4096 + r11);

        // ensure the ds_reads above retired before the DMA below can overwrite the slot
        asm volatile("s_waitcnt lgkmcnt(0)" ::: "memory");

        // ---- refill slot with next pair (skip when out of work) ----
        const bool more = (np < nPairs);
        if (more) stage(np, nuvA, nuvB);
        const int nnp = more ? grab() : np;   // next-next index, RTT hidden by compute

        bf16x8 B1aA, B1bA, B1aB, B1bB;
        #pragma unroll
        for (int j = 0; j < 4; ++j) {
            B1aA[j] = (__bf16)xaA[j];  B1aA[4 + j] = (__bf16)xbA[j];
            B1bA[j] = (__bf16)xcA[j];  B1bA[4 + j] = (__bf16)xdA[j];
            B1aB[j] = (__bf16)xaB[j];  B1aB[4 + j] = (__bf16)xbB[j];
            B1bB[j] = (__bf16)xcB[j];  B1bB[4 + j] = (__bf16)xdB[j];
        }

        // ---- fused trunk+head, W1/b1 fragments shared by both tiles ----
        f32x4 oaccA = {0.f, 0.f, 0.f, 0.f};
        f32x4 oaccB = {0.f, 0.f, 0.f, 0.f};
        #pragma unroll
        for (int s = 0; s < 4; ++s) {
            const int t0 = 2 * s, t1 = 2 * s + 1;
            f32x4 bia0 = *reinterpret_cast<const f32x4*>(&b1s[16 * t0 + 4 * g]); // bcast
            f32x4 bia1 = *reinterpret_cast<const f32x4*>(&b1s[16 * t1 + 4 * g]);
            const int lo0 = (16 * t0 + c) * 128 + 16 * g;
            const int lo1 = (16 * t1 + c) * 128 + 16 * g;
            short8 A00 = *reinterpret_cast<const short8*>(w1b + (lo0 ^ sw));
            short8 A01 = *reinterpret_cast<const short8*>(w1b + ((lo0 + 64) ^ sw));
            short8 A10 = *reinterpret_cast<const short8*>(w1b + (lo1 ^ sw));
            short8 A11 = *reinterpret_cast<const short8*>(w1b + ((lo1 + 64) ^ sw));
            f32x4 h0A = bia0, h1A = bia1, h0B = bia0, h1B = bia1;
            h0A = mfma16(__builtin_bit_cast(bf16x8, A00), B1aA, h0A);
            h0B = mfma16(__builtin_bit_cast(bf16x8, A00), B1aB, h0B);
            h1A = mfma16(__builtin_bit_cast(bf16x8, A10), B1aA, h1A);
            h1B = mfma16(__builtin_bit_cast(bf16x8, A10), B1aB, h1B);
            h0A = mfma16(__builtin_bit_cast(bf16x8, A01), B1bA, h0A);
            h0B = mfma16(__builtin_bit_cast(bf16x8, A01), B1bB, h0B);
            h1A = mfma16(__builtin_bit_cast(bf16x8, A11), B1bA, h1A);
            h1B = mfma16(__builtin_bit_cast(bf16x8, A11), B1bB, h1B);
            bf16x8 A2A, A2B;
            #pragma unroll
            for (int j = 0; j < 4; ++j) {
                A2A[j]     = (__bf16)fmaxf(h0A[j], 0.0f);
                A2A[4 + j] = (__bf16)fmaxf(h1A[j], 0.0f);
                A2B[j]     = (__bf16)fmaxf(h0B[j], 0.0f);
                A2B[4 + j] = (__bf16)fmaxf(h1B[j], 0.0f);
            }
            oaccA = mfma16(A2A, B2[s], oaccA);
            oaccB = mfma16(A2B, B2[s], oaccB);
        }

        // ---- per-row head select + store (each out element hits exactly 1 lane) ----
        const int m0 = p * 32 + 4 * g;          // tile A rows; tile B rows = +16
        if (khead == uvA[0]) out[(m0 +  0) * 2 + opos] = oaccA[0] + bbr;
        if (khead == uvA[1]) out[(m0 +  1) * 2 + opos] = oaccA[1] + bbr;
        if (khead == uvA[2]) out[(m0 +  2) * 2 + opos] = oaccA[2] + bbr;
        if (khead == uvA[3]) out[(m0 +  3) * 2 + opos] = oaccA[3] + bbr;
        if (khead == uvB[0]) out[(m0 + 16) * 2 + opos] = oaccB[0] + bbr;
        if (khead == uvB[1]) out[(m0 + 17) * 2 + opos] = oaccB[1] + bbr;
        if (khead == uvB[2]) out[(m0 + 18) * 2 + opos] = oaccB[2] + bbr;
        if (khead == uvB[3]) out[(m0 + 19) * 2 + opos] = oaccB[3] + bbr;

        if (!more) break;
        p = np; np = nnp; uvA = nuvA; uvB = nuvB;
    }
}

extern "C" void kernel_launch(void* const* d_in, const int* in_sizes, int n_in,
                              void* d_out, int out_size, void* d_ws, size_t ws_size,
                              hipStream_t stream) {
    const float* x  = (const float*)d_in[0];
    const int*   u  = (const int*)d_in[1];   // integer inputs are int32 on device
    const float* W1 = (const float*)d_in[2];
    const float* b1 = (const float*)d_in[3];
    const float* Wb = (const float*)d_in[4];
    const float* bb = (const float*)d_in[5];
    float* out = (float*)d_out;
    unsigned int* cnt = (unsigned int*)d_ws;

    const int B = in_sizes[1];        // u has one element per row
    const int nTiles = B / 16;        // 62,500 (exact)
    const int nPairs = nTiles / 2;    // 31,250 (exact)

    // zero the dynamic-work counter each launch (async memset is graph-capturable)
    hipMemsetAsync(cnt, 0, sizeof(unsigned int), stream);

    // LDS/block = 48.5KB -> 3 blocks/CU -> 768 blocks all co-resident (12 waves/CU),
    // each wave cycling one 8KB pair-slot, grabbing pairs dynamically.
    int blocks = 768;
    hipLaunchKernelGGL(coil_fused, dim3(blocks), dim3(256), 0, stream,
                       x, u, W1, b1, Wb, bb, out, cnt, nPairs);
}

// Round 10
// 84.911 us; speedup vs baseline: 4.8743x; 4.8743x over previous
//
#include <hip/hip_runtime.h>
#include <stdint.h>

// Problem: B=1,000,000 rows; IN=64, H=128, OUT=2, 3 heads, per-row routing u in [0,3).
// out[b,:] = Wb[u[b]] @ relu(W1 @ x[b] + b1) + bb[u[b]]
//
// Roofline: mandatory HBM = x(256MB) + u(4MB) + out(8MB) ~ 268MB -> ~43us @ 6.3TB/s.
//
// Journal:
//  R2:  99us. LDS-W1, x global->reg, no prefetch. Latency-bound, 2 grid rounds.
//  R3: 135us. Reg-prefetch + forced 64-VGPR cap -> spill. Cap was the bug, not prefetch.
//  R4: 343us. launch_bounds(256,8) -> VGPR 32 -> 225MB spill. Never force-shrink regs.
//  R5: 190us. waves_per_eu(4,4) -> still spilled. Attributes don't raise budgets.
//  R6:  61us. Per-wave LDS ring + global_load_lds (in-flight bytes in vmcnt queue).
//  R7:  53us. Pair-shared W1 reads + 1-ahead restage. ~5.0 TB/s effective.
//  R8:  56us. Quad slots halved waves/CU: concurrency > wait-distance. FALSIFIED
//       latency-exposure theory.
//  R9: 414us. Dynamic pair grabs via ONE global atomic: ~34K same-line atomics x 13ns
//       serialized the kernel. LESSONS: same-address atomic ~75M/s; uniform-work tails
//       self-balance in BW-bound kernels (stragglers inherit freed BW) -- dynamic
//       scheduling can't beat static +-1 anyway.
//  R10 (this): x direct global->VGPR with IN-PLACE rolling 1-tile prefetch (pack bf16
//       frags first -> f32 regs die -> overwrite with next tile's loads; load-use
//       distance = full compute). No x-LDS at all: LDS 16.9KB/block, VGPR ~100 ->
//       ~20 waves/CU (vs 12), continuous ~4KB/wave outstanding, no vmcnt(0) drains.
//       W1 LDS layout / MFMA bijections / store path identical to R7 (validated).

typedef float f32x4 __attribute__((ext_vector_type(4)));
typedef int   i32x4 __attribute__((ext_vector_type(4)));
typedef short short8 __attribute__((ext_vector_type(8)));
typedef __bf16 bf16x8 __attribute__((ext_vector_type(8)));

static __device__ __forceinline__ f32x4 mfma16(bf16x8 a, bf16x8 b, f32x4 c) {
    return __builtin_amdgcn_mfma_f32_16x16x32_bf16(a, b, c, 0, 0, 0);
}

// MFMA k-packing: any bijection (gamma=lane>>4, j)->k works if A and B use the same one.
// Trunk (K=32 step s): k = 32s + 8g + j. D: col=lane&15=batch row, row = h-dim 16t+4g+r.
// Head: A2 row = batch row (matches trunk D -> zero cross-lane movement); k-bijection
//   n = 32s + 16*(j>>2) + 4g + (j&3) = exactly the h-dims this lane holds.
//   D2: col=lane&15 = head*2+out combo (<6), row -> batch row base+4g+r.
__global__ __launch_bounds__(256) void coil_fused(
    const float* __restrict__ x,
    const int*   __restrict__ u,    // routing ids, int32 on device
    const float* __restrict__ W1,   // [128][64]
    const float* __restrict__ b1,   // [128]
    const float* __restrict__ Wb,   // [3][2][128]
    const float* __restrict__ bb,   // [3][2]
    float* __restrict__ out,        // [B][2]
    int nTiles, int nWaves)
{
    __shared__ short w1s[128 * 64];   // 16 KB: W1 as bf16, XOR-swizzled rows
    __shared__ float b1s[128];

    const int tid  = threadIdx.x;
    const int lane = tid & 63;
    const int c    = lane & 15;       // MFMA "parallel" index
    const int g    = lane >> 4;       // k-group gamma

    // ---- contiguous chunk per wave (computed first so first loads issue ASAP) ----
    const int w = blockIdx.x * 4 + (tid >> 6);
    const int q = nTiles / nWaves, rm = nTiles % nWaves;
    int tile       = w * q + (w < rm ? w : rm);
    const int tend = tile + q + (w < rm ? 1 : 0);

    // ---- prologue: first tile's x/u loads in flight while W1 stages ----
    f32x4 xa, xb, xc, xd;             // lane's batch row = tile*16 + c; k = 32s + 8g + j
    i32x4 uv;
    {
        const float* xr = x + (size_t)(tile * 16 + c) * 64 + 8 * g;
        xa = *reinterpret_cast<const f32x4*>(xr);       // s=0, j=0..3
        xb = *reinterpret_cast<const f32x4*>(xr + 4);   // s=0, j=4..7
        xc = *reinterpret_cast<const f32x4*>(xr + 32);  // s=1, j=0..3
        xd = *reinterpret_cast<const f32x4*>(xr + 36);  // s=1, j=4..7
        uv = *reinterpret_cast<const i32x4*>(u + tile * 16 + 4 * g);
    }

    // ---- stage W1 into LDS as bf16, swizzled: phys = logical ^ ((row&7)<<4) ----
    for (int qq = tid; qq < 1024; qq += 256) {
        int row = qq >> 3;
        const float* src = W1 + row * 64 + (qq & 7) * 8;
        short8 v;
        #pragma unroll
        for (int j = 0; j < 8; ++j) v[j] = __builtin_bit_cast(short, (__bf16)src[j]);
        int phys = (qq * 16) ^ ((row & 7) << 4);
        *reinterpret_cast<short8*>(reinterpret_cast<char*>(w1s) + phys) = v;
    }
    if (tid < 128) b1s[tid] = b1[tid];

    // ---- loop-invariant head-weight fragments (16 VGPR) + head bias ----
    const int ko = c;                  // combo = head*2 + out_pos; valid if < 6
    const bool kvalid = (ko < 6);
    bf16x8 B2[4];
    #pragma unroll
    for (int s = 0; s < 4; ++s) {
        #pragma unroll
        for (int j = 0; j < 8; ++j) {
            int n = 32 * s + ((j >> 2) << 4) + 4 * g + (j & 3);
            B2[s][j] = kvalid ? (__bf16)Wb[ko * 128 + n] : (__bf16)0.0f;
        }
    }
    const float bbr = kvalid ? bb[ko] : 0.0f;
    const int khead = ko >> 1, opos = ko & 1;

    __syncthreads();   // only barrier in the kernel

    const char* w1b = reinterpret_cast<const char*>(w1s);
    const int sw = (c & 7) << 4;

    for (;;) {
        // ---- pack current tile's fragments (f32 x regs die here) ----
        bf16x8 B1a, B1b;
        #pragma unroll
        for (int j = 0; j < 4; ++j) {
            B1a[j]     = (__bf16)xa[j];
            B1a[4 + j] = (__bf16)xb[j];
            B1b[j]     = (__bf16)xc[j];
            B1b[4 + j] = (__bf16)xd[j];
        }
        const i32x4 uvc = uv;
        const int m0 = tile * 16 + 4 * g;

        // ---- in-place rolling prefetch of the next tile (load-use = full compute) ----
        ++tile;
        const bool more = (tile < tend);
        if (more) {
            const float* xr = x + (size_t)(tile * 16 + c) * 64 + 8 * g;
            xa = *reinterpret_cast<const f32x4*>(xr);
            xb = *reinterpret_cast<const f32x4*>(xr + 4);
            xc = *reinterpret_cast<const f32x4*>(xr + 32);
            xd = *reinterpret_cast<const f32x4*>(xr + 36);
            uv = *reinterpret_cast<const i32x4*>(u + tile * 16 + 4 * g);
        }

        // ---- fused trunk+head: per head-K-step s, only h[2s],h[2s+1] live ----
        f32x4 oacc = {0.f, 0.f, 0.f, 0.f};
        #pragma unroll
        for (int s = 0; s < 4; ++s) {
            const int t0 = 2 * s, t1 = 2 * s + 1;
            f32x4 h0 = *reinterpret_cast<const f32x4*>(&b1s[16 * t0 + 4 * g]); // bcast
            f32x4 h1 = *reinterpret_cast<const f32x4*>(&b1s[16 * t1 + 4 * g]);
            const int lo0 = (16 * t0 + c) * 128 + 16 * g;
            const int lo1 = (16 * t1 + c) * 128 + 16 * g;
            short8 A00 = *reinterpret_cast<const short8*>(w1b + (lo0 ^ sw));
            short8 A01 = *reinterpret_cast<const short8*>(w1b + ((lo0 + 64) ^ sw));
            short8 A10 = *reinterpret_cast<const short8*>(w1b + (lo1 ^ sw));
            short8 A11 = *reinterpret_cast<const short8*>(w1b + ((lo1 + 64) ^ sw));
            h0 = mfma16(__builtin_bit_cast(bf16x8, A00), B1a, h0);
            h1 = mfma16(__builtin_bit_cast(bf16x8, A10), B1a, h1);
            h0 = mfma16(__builtin_bit_cast(bf16x8, A01), B1b, h0);
            h1 = mfma16(__builtin_bit_cast(bf16x8, A11), B1b, h1);
            bf16x8 A2;
            #pragma unroll
            for (int j = 0; j < 4; ++j) {
                A2[j]     = (__bf16)fmaxf(h0[j], 0.0f);
                A2[4 + j] = (__bf16)fmaxf(h1[j], 0.0f);
            }
            oacc = mfma16(A2, B2[s], oacc);
        }

        // ---- per-row head select + store (each out element hits exactly 1 lane) ----
        if (khead == uvc[0]) out[(m0 + 0) * 2 + opos] = oacc[0] + bbr;
        if (khead == uvc[1]) out[(m0 + 1) * 2 + opos] = oacc[1] + bbr;
        if (khead == uvc[2]) out[(m0 + 2) * 2 + opos] = oacc[2] + bbr;
        if (khead == uvc[3]) out[(m0 + 3) * 2 + opos] = oacc[3] + bbr;

        if (!more) break;
    }
}

extern "C" void kernel_launch(void* const* d_in, const int* in_sizes, int n_in,
                              void* d_out, int out_size, void* d_ws, size_t ws_size,
                              hipStream_t stream) {
    const float* x  = (const float*)d_in[0];
    const int*   u  = (const int*)d_in[1];   // integer inputs are int32 on device
    const float* W1 = (const float*)d_in[2];
    const float* b1 = (const float*)d_in[3];
    const float* Wb = (const float*)d_in[4];
    const float* bb = (const float*)d_in[5];
    float* out = (float*)d_out;

    const int B = in_sizes[1];        // u has one element per row
    const int nTiles = B / 16;        // 62,500 (exact)

    // LDS only 16.9KB/block, VGPR ~100 -> up to 5 blocks/CU (20 waves/CU). Launch
    // 1280 blocks; if only 4/CU fit, queued blocks backfill (self-balancing).
    int blocks = 1280;
    int nWaves = blocks * 4;
    if (nWaves > nTiles) { blocks = (nTiles + 3) / 4; nWaves = blocks * 4; }

    hipLaunchKernelGGL(coil_fused, dim3(blocks), dim3(256), 0, stream,
                       x, u, W1, b1, Wb, bb, out, nTiles, nWaves);
}

// Round 11
// 68.818 us; speedup vs baseline: 6.0142x; 1.2339x over previous
//
#include <hip/hip_runtime.h>
#include <stdint.h>

// Problem: B=1,000,000 rows; IN=64, H=128, OUT=2, 3 heads, per-row routing u in [0,3).
// out[b,:] = Wb[u[b]] @ relu(W1 @ x[b] + b1) + bb[u[b]]
//
// Roofline: mandatory HBM = x(256MB) + u(4MB) + out(8MB) ~ 268MB -> ~43us @ 6.3TB/s.
//
// Journal:
//  R2:  99us. LDS-W1, x global->reg, no prefetch. Latency-bound.
//  R3: 135us. Reg-prefetch + forced 64-VGPR cap -> spill. Cap was the bug.
//  R4: 343us. launch_bounds(256,8) -> VGPR 32 -> 225MB spill writes.
//  R5: 190us. waves_per_eu(4,4) + W1-in-regs -> allocator pinned to 64, spilled.
//       The ATTRIBUTE poisoned it, not the reg-hoist.
//  R6:  61us. Per-wave LDS ring + global_load_lds: in-flight bytes in the vmcnt
//       queue, not VGPRs. WIN.
//  R7:  53us. Pair-shared W1 reads + 1-ahead single-slot restage. ~5.0 TB/s eff.
//  R8:  56us. Quad slots halved waves/CU: concurrency > wait-distance.
//  R9: 414us. One global atomic per pair serialized everything (~75M/s same-line).
//  R10: 85us. Direct global->reg x prefetch loses to LDS-DMA staging (register
//       live-set + conservative waits vs zero-cost vmcnt queue).
//  R11 (this): R7's x path UNCHANGED (proven); W1 moved from LDS to 64 loop-invariant
//       VGPRs loaded once in the prologue (R5's idea minus the poison attribute).
//       Per-pair LDS ops 32 -> 16, no in-loop XOR addressing. Tile-sequential compute
//       caps live h-regs at 8 -> natural VGPR ~140, no caps, no spill. 128-thr blocks
//       (16.6KB LDS) -> residency VGPR-bound 12-16 waves/CU; 1536 blocks single-round.

typedef float f32x4 __attribute__((ext_vector_type(4)));
typedef int   i32x4 __attribute__((ext_vector_type(4)));
typedef short short8 __attribute__((ext_vector_type(8)));
typedef __bf16 bf16x8 __attribute__((ext_vector_type(8)));

#define GLOBAL_AS __attribute__((address_space(1)))
#define LDS_AS    __attribute__((address_space(3)))

static __device__ __forceinline__ f32x4 mfma16(bf16x8 a, bf16x8 b, f32x4 c) {
    return __builtin_amdgcn_mfma_f32_16x16x32_bf16(a, b, c, 0, 0, 0);
}

// MFMA k-packing: any bijection (gamma=lane>>4, j)->k works if A and B use the same one.
// Trunk (K=32 step s): k = 32s + 8g + j. D: col=lane&15=batch row, row = h-dim 16t+4g+r.
// Head: A2 row = batch row (matches trunk D -> zero cross-lane movement); k-bijection
//   n = 32s + 16*(j>>2) + 4g + (j&3) = exactly the h-dims this lane holds.
//   D2: col=lane&15 = head*2+out combo (<6), row -> batch row base+4g+r.
__global__ __launch_bounds__(128) void coil_fused(
    const float* __restrict__ x,
    const int*   __restrict__ u,    // routing ids, int32 on device
    const float* __restrict__ W1,   // [128][64]
    const float* __restrict__ b1,   // [128]
    const float* __restrict__ Wb,   // [3][2][128]
    const float* __restrict__ bb,   // [3][2]
    float* __restrict__ out,        // [B][2]
    int nPairs, int nWaves)
{
    __shared__ float b1s[128];
    __shared__ float xsl[2][2048];    // 16 KB: per-wave pair slot (8KB each)

    const int tid  = threadIdx.x;
    const int lane = tid & 63;
    const int c    = lane & 15;       // MFMA "parallel" index
    const int g    = lane >> 4;       // k-group gamma
    const int wsl  = tid >> 6;        // wave slot within block (0/1)

    // ---- per-lane pre-swizzled GLOBAL offsets for x staging (8 chunks of 1KB) ----
    // LDS phys byte P = i*1024 + lane*16 holds x logical byte P ^ (((P>>8)&7)<<4)
    // (XOR touches bits 4-6 only; row bits unaffected).
    int xoff[8];
    #pragma unroll
    for (int i = 0; i < 8; ++i) {
        int pb = i * 1024 + lane * 16;
        xoff[i] = pb ^ (((pb >> 8) & 7) << 4);
    }

    const char* xb8 = reinterpret_cast<const char*>(x);
    float* slot = &xsl[wsl][0];
    LDS_AS char* dst = (LDS_AS char*)slot;
    const char* sb = reinterpret_cast<const char*>(slot);

    auto stage = [&](int pairIdx, i32x4& uvA, i32x4& uvB) {
        const int t0 = pairIdx * 2;
        uvA = *reinterpret_cast<const i32x4*>(u + t0 * 16 + 4 * g);
        uvB = *reinterpret_cast<const i32x4*>(u + t0 * 16 + 16 + 4 * g);
        const char* src = xb8 + (size_t)t0 * 4096;
        #pragma unroll
        for (int i = 0; i < 8; ++i)
            __builtin_amdgcn_global_load_lds((const GLOBAL_AS void*)(src + xoff[i]),
                                             (LDS_AS void*)(dst + i * 1024), 16, 0, 0);
    };

    // ---- contiguous pair chunk per wave; first stage issued ASAP (overlaps prologue) ----
    const int w = blockIdx.x * 2 + wsl;
    const int qv = nPairs / nWaves, rm = nPairs % nWaves;
    int p          = w * qv + (w < rm ? w : rm);
    const int pend = p + qv + (w < rm ? 1 : 0);

    i32x4 uvA, uvB, nuvA, nuvB;
    if (p < pend) stage(p, uvA, uvB);

    // ---- loop-invariant W1 A-fragments in registers (64 VGPR), loaded once ----
    // A0[t]: row 16t+c, k = 8g+j ; A1[t]: row 16t+c, k = 32+8g+j
    bf16x8 A0[8], A1[8];
    {
        const float* wr = W1 + c * 64 + 8 * g;   // + t*1024 floats per t
        #pragma unroll
        for (int t = 0; t < 8; ++t) {
            f32x4 p0 = *reinterpret_cast<const f32x4*>(wr + t * 1024);
            f32x4 p1 = *reinterpret_cast<const f32x4*>(wr + t * 1024 + 4);
            f32x4 p2 = *reinterpret_cast<const f32x4*>(wr + t * 1024 + 32);
            f32x4 p3 = *reinterpret_cast<const f32x4*>(wr + t * 1024 + 36);
            #pragma unroll
            for (int j = 0; j < 4; ++j) {
                A0[t][j]     = (__bf16)p0[j];
                A0[t][4 + j] = (__bf16)p1[j];
                A1[t][j]     = (__bf16)p2[j];
                A1[t][4 + j] = (__bf16)p3[j];
            }
        }
    }

    // ---- loop-invariant head-weight fragments (16 VGPR) + head bias ----
    const int ko = c;                  // combo = head*2 + out_pos; valid if < 6
    const bool kvalid = (ko < 6);
    bf16x8 B2[4];
    #pragma unroll
    for (int s = 0; s < 4; ++s) {
        #pragma unroll
        for (int j = 0; j < 8; ++j) {
            int n = 32 * s + ((j >> 2) << 4) + 4 * g + (j & 3);
            B2[s][j] = kvalid ? (__bf16)Wb[ko * 128 + n] : (__bf16)0.0f;
        }
    }
    const float bbr = kvalid ? bb[ko] : 0.0f;
    const int khead = ko >> 1, opos = ko & 1;

    b1s[tid] = b1[tid];               // 128 threads cover 128 entries
    __syncthreads();                  // only barrier in the kernel

    if (p >= pend) return;

    // ---- x read offsets within the slot (bytes), swizzle-corrected; tile B = +4096 ----
    const int sw  = (c & 7) << 4;
    const int r00 = (c * 256 + g * 32 +   0) ^ sw;   // s=0, j=0..3
    const int r01 = (c * 256 + g * 32 +  16) ^ sw;   // s=0, j=4..7
    const int r10 = (c * 256 + g * 32 + 128) ^ sw;   // s=1, j=0..3
    const int r11 = (c * 256 + g * 32 + 144) ^ sw;   // s=1, j=4..7

    for (; p < pend; ++p) {
        // ---- read both tiles' x fragments (waits on this slot's in-flight DMA) ----
        f32x4 xaA = *reinterpret_cast<const f32x4*>(sb + r00);
        f32x4 xbA = *reinterpret_cast<const f32x4*>(sb + r01);
        f32x4 xcA = *reinterpret_cast<const f32x4*>(sb + r10);
        f32x4 xdA = *reinterpret_cast<const f32x4*>(sb + r11);
        f32x4 xaB = *reinterpret_cast<const f32x4*>(sb + 4096 + r00);
        f32x4 xbB = *reinterpret_cast<const f32x4*>(sb + 4096 + r01);
        f32x4 xcB = *reinterpret_cast<const f32x4*>(sb + 4096 + r10);
        f32x4 xdB = *reinterpret_cast<const f32x4*>(sb + 4096 + r11);

        // ensure the ds_reads above retired before the DMA below can overwrite the slot
        asm volatile("s_waitcnt lgkmcnt(0)" ::: "memory");

        // ---- refill slot with next pair (skip on last iteration) ----
        if (p + 1 < pend) stage(p + 1, nuvA, nuvB);

        bf16x8 B1aA, B1bA, B1aB, B1bB;
        #pragma unroll
        for (int j = 0; j < 4; ++j) {
            B1aA[j] = (__bf16)xaA[j];  B1aA[4 + j] = (__bf16)xbA[j];
            B1bA[j] = (__bf16)xcA[j];  B1bA[4 + j] = (__bf16)xdA[j];
            B1aB[j] = (__bf16)xaB[j];  B1aB[4 + j] = (__bf16)xbB[j];
            B1bB[j] = (__bf16)xcB[j];  B1bB[4 + j] = (__bf16)xdB[j];
        }

        // ---- fused trunk+head, tile-sequential (A then B): peak live h-regs = 8 ----
        f32x4 oaccA = {0.f, 0.f, 0.f, 0.f};
        f32x4 oaccB = {0.f, 0.f, 0.f, 0.f};
        #pragma unroll
        for (int s = 0; s < 4; ++s) {
            const int t0 = 2 * s, t1 = 2 * s + 1;
            f32x4 bia0 = *reinterpret_cast<const f32x4*>(&b1s[16 * t0 + 4 * g]); // bcast
            f32x4 bia1 = *reinterpret_cast<const f32x4*>(&b1s[16 * t1 + 4 * g]);
            f32x4 h0 = bia0, h1 = bia1;
            h0 = mfma16(A0[t0], B1aA, h0);
            h1 = mfma16(A0[t1], B1aA, h1);
            h0 = mfma16(A1[t0], B1bA, h0);
            h1 = mfma16(A1[t1], B1bA, h1);
            bf16x8 A2;
            #pragma unroll
            for (int j = 0; j < 4; ++j) {
                A2[j]     = (__bf16)fmaxf(h0[j], 0.0f);
                A2[4 + j] = (__bf16)fmaxf(h1[j], 0.0f);
            }
            oaccA = mfma16(A2, B2[s], oaccA);
            h0 = bia0; h1 = bia1;
            h0 = mfma16(A0[t0], B1aB, h0);
            h1 = mfma16(A0[t1], B1aB, h1);
            h0 = mfma16(A1[t0], B1bB, h0);
            h1 = mfma16(A1[t1], B1bB, h1);
            #pragma unroll
            for (int j = 0; j < 4; ++j) {
                A2[j]     = (__bf16)fmaxf(h0[j], 0.0f);
                A2[4 + j] = (__bf16)fmaxf(h1[j], 0.0f);
            }
            oaccB = mfma16(A2, B2[s], oaccB);
        }

        // ---- per-row head select + store (each out element hits exactly 1 lane) ----
        const int m0 = p * 32 + 4 * g;          // tile A rows; tile B rows = +16
        if (khead == uvA[0]) out[(m0 +  0) * 2 + opos] = oaccA[0] + bbr;
        if (khead == uvA[1]) out[(m0 +  1) * 2 + opos] = oaccA[1] + bbr;
        if (khead == uvA[2]) out[(m0 +  2) * 2 + opos] = oaccA[2] + bbr;
        if (khead == uvA[3]) out[(m0 +  3) * 2 + opos] = oaccA[3] + bbr;
        if (khead == uvB[0]) out[(m0 + 16) * 2 + opos] = oaccB[0] + bbr;
        if (khead == uvB[1]) out[(m0 + 17) * 2 + opos] = oaccB[1] + bbr;
        if (khead == uvB[2]) out[(m0 + 18) * 2 + opos] = oaccB[2] + bbr;
        if (khead == uvB[3]) out[(m0 + 19) * 2 + opos] = oaccB[3] + bbr;

        uvA = nuvA; uvB = nuvB;
    }
}

extern "C" void kernel_launch(void* const* d_in, const int* in_sizes, int n_in,
                              void* d_out, int out_size, void* d_ws, size_t ws_size,
                              hipStream_t stream) {
    const float* x  = (const float*)d_in[0];
    const int*   u  = (const int*)d_in[1];   // integer inputs are int32 on device
    const float* W1 = (const float*)d_in[2];
    const float* b1 = (const float*)d_in[3];
    const float* Wb = (const float*)d_in[4];
    const float* bb = (const float*)d_in[5];
    float* out = (float*)d_out;

    const int B = in_sizes[1];        // u has one element per row
    const int nTiles = B / 16;        // 62,500 (exact)
    const int nPairs = nTiles / 2;    // 31,250 (exact)

    // 128-thr blocks, LDS 16.6KB. Residency VGPR-bound: ~140 VGPR -> 3 waves/SIMD
    // -> 6 blocks/CU -> 1536 blocks all co-resident (single round), ~10 pairs/wave.
    int blocks = 1536;
    int nWaves = blocks * 2;
    if (nWaves > nPairs) { blocks = (nPairs + 1) / 2; nWaves = blocks * 2; }

    hipLaunchKernelGGL(coil_fused, dim3(blocks), dim3(128), 0, stream,
                       x, u, W1, b1, Wb, bb, out, nPairs, nWaves);
}

// Round 12
// 61.059 us; speedup vs baseline: 6.7785x; 1.1271x over previous
//
#include <hip/hip_runtime.h>
#include <stdint.h>

// Problem: B=1,000,000 rows; IN=64, H=128, OUT=2, 3 heads, per-row routing u in [0,3).
// out[b,:] = Wb[u[b]] @ relu(W1 @ x[b] + b1) + bb[u[b]]
//
// Roofline: mandatory HBM = x(256MB) + u(4MB) + out(8MB) ~ 268MB -> ~43us @ 6.3TB/s
// (L3 retains ~half of x across replays, so true HBM fetch ~140MB; measured R2/R9).
//
// Journal:
//  R2:  99us. LDS-W1, x global->reg, no prefetch. Latency-bound.
//  R3: 135us. Reg-prefetch + forced 64-VGPR cap -> spill. Cap was the bug.
//  R4: 343us. launch_bounds(256,8) -> VGPR 32 -> 225MB spill writes.
//  R5: 190us. waves_per_eu(4,4) -> allocator pinned 64, spilled. Attributes poison.
//  R6:  61us. Per-wave LDS ring + global_load_lds (bytes live in vmcnt queue). WIN.
//  R7:  53us. Pair-shared W1 reads + 1-ahead single-slot restage. CHAMPION.
//       ~5.0 TB/s apparent (268MB/53us); 12 waves/CU, LDS-bound residency.
//  R8:  56us. Quad slots halved waves/CU: concurrency > wait-distance.
//  R9: 414us. One global atomic per pair serialized all (~75M/s same-line atomics).
//  R10: 85us. Direct global->reg x prefetch loses to LDS-DMA staging.
//  R11: 69us. W1-in-regs FROM GLOBAL: 96MB prologue storm + VGPR/wave loss +
//       tile-sequential confound. Hoist idea not yet cleanly tested.
//  R12 (this): R7 byte-identical structure (256-thr blocks, 48.5KB LDS, 12 waves/CU
//       LDS-bound -> VGPR headroom to 168 free) + W1 A-fragments hoisted ONCE from
//       LDS into 64 VGPRs after the barrier. In-loop LDS ops 32 -> 16/pair; W1
//       XOR-addressing VALU leaves the loop. B1 packed BEFORE the lgkm fence (per-use
//       dep waits drain lgkm; x-frag regs die before stage() -> peak VGPR ~145).

typedef float f32x4 __attribute__((ext_vector_type(4)));
typedef int   i32x4 __attribute__((ext_vector_type(4)));
typedef short short8 __attribute__((ext_vector_type(8)));
typedef __bf16 bf16x8 __attribute__((ext_vector_type(8)));

#define GLOBAL_AS __attribute__((address_space(1)))
#define LDS_AS    __attribute__((address_space(3)))

static __device__ __forceinline__ f32x4 mfma16(bf16x8 a, bf16x8 b, f32x4 c) {
    return __builtin_amdgcn_mfma_f32_16x16x32_bf16(a, b, c, 0, 0, 0);
}

// MFMA k-packing: any bijection (gamma=lane>>4, j)->k works if A and B use the same one.
// Trunk (K=32 step s): k = 32s + 8g + j. D: col=lane&15=batch row, row = h-dim 16t+4g+r.
// Head: A2 row = batch row (matches trunk D -> zero cross-lane movement); k-bijection
//   n = 32s + 16*(j>>2) + 4g + (j&3) = exactly the h-dims this lane holds.
//   D2: col=lane&15 = head*2+out combo (<6), row -> batch row base+4g+r.
__global__ __launch_bounds__(256) void coil_fused(
    const float* __restrict__ x,
    const int*   __restrict__ u,    // routing ids, int32 on device
    const float* __restrict__ W1,   // [128][64]
    const float* __restrict__ b1,   // [128]
    const float* __restrict__ Wb,   // [3][2][128]
    const float* __restrict__ bb,   // [3][2]
    float* __restrict__ out,        // [B][2]
    int nPairs, int nWaves)
{
    __shared__ short w1s[128 * 64];   // 16 KB: W1 as bf16, XOR-swizzled rows
    __shared__ float b1s[128];
    __shared__ float xsl[4][2048];    // 32 KB: per-wave pair slot (8KB each)

    const int tid  = threadIdx.x;
    const int lane = tid & 63;
    const int c    = lane & 15;       // MFMA "parallel" index
    const int g    = lane >> 4;       // k-group gamma
    const int wsl  = tid >> 6;        // wave slot within block

    // ---- stage W1 into LDS as bf16, swizzled: phys = logical ^ ((row&7)<<4) ----
    for (int qq = tid; qq < 1024; qq += 256) {
        int row = qq >> 3;
        const float* src = W1 + row * 64 + (qq & 7) * 8;
        short8 v;
        #pragma unroll
        for (int j = 0; j < 8; ++j) v[j] = __builtin_bit_cast(short, (__bf16)src[j]);
        int phys = (qq * 16) ^ ((row & 7) << 4);
        *reinterpret_cast<short8*>(reinterpret_cast<char*>(w1s) + phys) = v;
    }
    if (tid < 128) b1s[tid] = b1[tid];

    // ---- loop-invariant head-weight fragments (16 VGPR) + head bias ----
    const int ko = c;                  // combo = head*2 + out_pos; valid if < 6
    const bool kvalid = (ko < 6);
    bf16x8 B2[4];
    #pragma unroll
    for (int s = 0; s < 4; ++s) {
        #pragma unroll
        for (int j = 0; j < 8; ++j) {
            int n = 32 * s + ((j >> 2) << 4) + 4 * g + (j & 3);
            B2[s][j] = kvalid ? (__bf16)Wb[ko * 128 + n] : (__bf16)0.0f;
        }
    }
    const float bbr = kvalid ? bb[ko] : 0.0f;
    const int khead = ko >> 1, opos = ko & 1;

    __syncthreads();   // only barrier in the kernel

    // ---- per-lane pre-swizzled GLOBAL offsets for x staging (8 chunks of 1KB) ----
    // LDS phys byte P = i*1024 + lane*16 holds x logical byte P ^ (((P>>8)&7)<<4)
    // (XOR touches bits 4-6 only; row bits unaffected).
    int xoff[8];
    #pragma unroll
    for (int i = 0; i < 8; ++i) {
        int pb = i * 1024 + lane * 16;
        xoff[i] = pb ^ (((pb >> 8) & 7) << 4);
    }

    // ---- x read offsets within the slot (bytes), swizzle-corrected; tile B = +4096 ----
    const int sw  = (c & 7) << 4;
    const int r00 = (c * 256 + g * 32 +   0) ^ sw;   // s=0, j=0..3
    const int r01 = (c * 256 + g * 32 +  16) ^ sw;   // s=0, j=4..7
    const int r10 = (c * 256 + g * 32 + 128) ^ sw;   // s=1, j=0..3
    const int r11 = (c * 256 + g * 32 + 144) ^ sw;   // s=1, j=4..7

    const char* xb8 = reinterpret_cast<const char*>(x);
    const char* w1b = reinterpret_cast<const char*>(w1s);
    float* slot = &xsl[wsl][0];
    LDS_AS char* dst = (LDS_AS char*)slot;
    const char* sb = reinterpret_cast<const char*>(slot);

    auto stage = [&](int pairIdx, i32x4& uvA, i32x4& uvB) {
        const int t0 = pairIdx * 2;
        uvA = *reinterpret_cast<const i32x4*>(u + t0 * 16 + 4 * g);
        uvB = *reinterpret_cast<const i32x4*>(u + t0 * 16 + 16 + 4 * g);
        const char* src = xb8 + (size_t)t0 * 4096;
        #pragma unroll
        for (int i = 0; i < 8; ++i)
            __builtin_amdgcn_global_load_lds((const GLOBAL_AS void*)(src + xoff[i]),
                                             (LDS_AS void*)(dst + i * 1024), 16, 0, 0);
    };

    // ---- contiguous pair chunk per wave ----
    const int w = blockIdx.x * 4 + wsl;
    const int qv = nPairs / nWaves, rm = nPairs % nWaves;
    int p          = w * qv + (w < rm ? w : rm);
    const int pend = p + qv + (w < rm ? 1 : 0);
    if (p >= pend) return;

    i32x4 uvA, uvB, nuvA, nuvB;
    stage(p, uvA, uvB);   // issue first DMA ASAP (overlaps A-fragment hoist below)

    // ---- hoist loop-invariant W1 A-fragments from LDS into 64 VGPRs (once) ----
    // A0[t]: row 16t+c, k = 8g+j ; A1[t]: row 16t+c, k = 32+8g+j
    bf16x8 A0[8], A1[8];
    #pragma unroll
    for (int t = 0; t < 8; ++t) {
        const int lo = (16 * t + c) * 128 + 16 * g;
        A0[t] = __builtin_bit_cast(bf16x8, *reinterpret_cast<const short8*>(w1b + (lo ^ sw)));
        A1[t] = __builtin_bit_cast(bf16x8, *reinterpret_cast<const short8*>(w1b + ((lo + 64) ^ sw)));
    }

    for (; p < pend; ++p) {
        // ---- read both tiles' x fragments (waits on this slot's in-flight DMA) ----
        f32x4 xaA = *reinterpret_cast<const f32x4*>(sb + r00);
        f32x4 xbA = *reinterpret_cast<const f32x4*>(sb + r01);
        f32x4 xcA = *reinterpret_cast<const f32x4*>(sb + r10);
        f32x4 xdA = *reinterpret_cast<const f32x4*>(sb + r11);
        f32x4 xaB = *reinterpret_cast<const f32x4*>(sb + 4096 + r00);
        f32x4 xbB = *reinterpret_cast<const f32x4*>(sb + 4096 + r01);
        f32x4 xcB = *reinterpret_cast<const f32x4*>(sb + 4096 + r10);
        f32x4 xdB = *reinterpret_cast<const f32x4*>(sb + 4096 + r11);

        // ---- pack B1 first: per-use dep waits retire all ds_reads; x-regs die here ----
        bf16x8 B1aA, B1bA, B1aB, B1bB;
        #pragma unroll
        for (int j = 0; j < 4; ++j) {
            B1aA[j] = (__bf16)xaA[j];  B1aA[4 + j] = (__bf16)xbA[j];
            B1bA[j] = (__bf16)xcA[j];  B1bA[4 + j] = (__bf16)xdA[j];
            B1aB[j] = (__bf16)xaB[j];  B1aB[4 + j] = (__bf16)xbB[j];
            B1bB[j] = (__bf16)xcB[j];  B1bB[4 + j] = (__bf16)xdB[j];
        }

        // ensure all slot reads retired before the DMA below can overwrite the slot
        // (free by now: every loaded value was consumed above)
        asm volatile("s_waitcnt lgkmcnt(0)" ::: "memory");

        // ---- refill slot with next pair (skip on last iteration) ----
        if (p + 1 < pend) stage(p + 1, nuvA, nuvB);

        // ---- fused trunk+head, W1 fragments from registers, interleaved A/B ----
        f32x4 oaccA = {0.f, 0.f, 0.f, 0.f};
        f32x4 oaccB = {0.f, 0.f, 0.f, 0.f};
        #pragma unroll
        for (int s = 0; s < 4; ++s) {
            const int t0 = 2 * s, t1 = 2 * s + 1;
            f32x4 bia0 = *reinterpret_cast<const f32x4*>(&b1s[16 * t0 + 4 * g]); // bcast
            f32x4 bia1 = *reinterpret_cast<const f32x4*>(&b1s[16 * t1 + 4 * g]);
            f32x4 h0A = bia0, h1A = bia1, h0B = bia0, h1B = bia1;
            h0A = mfma16(A0[t0], B1aA, h0A);
            h0B = mfma16(A0[t0], B1aB, h0B);
            h1A = mfma16(A0[t1], B1aA, h1A);
            h1B = mfma16(A0[t1], B1aB, h1B);
            h0A = mfma16(A1[t0], B1bA, h0A);
            h0B = mfma16(A1[t0], B1bB, h0B);
            h1A = mfma16(A1[t1], B1bA, h1A);
            h1B = mfma16(A1[t1], B1bB, h1B);
            bf16x8 A2A, A2B;
            #pragma unroll
            for (int j = 0; j < 4; ++j) {
                A2A[j]     = (__bf16)fmaxf(h0A[j], 0.0f);
                A2A[4 + j] = (__bf16)fmaxf(h1A[j], 0.0f);
                A2B[j]     = (__bf16)fmaxf(h0B[j], 0.0f);
                A2B[4 + j] = (__bf16)fmaxf(h1B[j], 0.0f);
            }
            oaccA = mfma16(A2A, B2[s], oaccA);
            oaccB = mfma16(A2B, B2[s], oaccB);
        }

        // ---- per-row head select + store (each out element hits exactly 1 lane) ----
        const int m0 = p * 32 + 4 * g;          // tile A rows; tile B rows = +16
        if (khead == uvA[0]) out[(m0 +  0) * 2 + opos] = oaccA[0] + bbr;
        if (khead == uvA[1]) out[(m0 +  1) * 2 + opos] = oaccA[1] + bbr;
        if (khead == uvA[2]) out[(m0 +  2) * 2 + opos] = oaccA[2] + bbr;
        if (khead == uvA[3]) out[(m0 +  3) * 2 + opos] = oaccA[3] + bbr;
        if (khead == uvB[0]) out[(m0 + 16) * 2 + opos] = oaccB[0] + bbr;
        if (khead == uvB[1]) out[(m0 + 17) * 2 + opos] = oaccB[1] + bbr;
        if (khead == uvB[2]) out[(m0 + 18) * 2 + opos] = oaccB[2] + bbr;
        if (khead == uvB[3]) out[(m0 + 19) * 2 + opos] = oaccB[3] + bbr;

        uvA = nuvA; uvB = nuvB;
    }
}

extern "C" void kernel_launch(void* const* d_in, const int* in_sizes, int n_in,
                              void* d_out, int out_size, void* d_ws, size_t ws_size,
                              hipStream_t stream) {
    const float* x  = (const float*)d_in[0];
    const int*   u  = (const int*)d_in[1];   // integer inputs are int32 on device
    const float* W1 = (const float*)d_in[2];
    const float* b1 = (const float*)d_in[3];
    const float* Wb = (const float*)d_in[4];
    const float* bb = (const float*)d_in[5];
    float* out = (float*)d_out;

    const int B = in_sizes[1];        // u has one element per row
    const int nTiles = B / 16;        // 62,500 (exact)
    const int nPairs = nTiles / 2;    // 31,250 (exact)

    // LDS/block = 48.5KB -> 3 blocks/CU -> 768 blocks all co-resident (12 waves/CU,
    // LDS-bound: VGPR free up to 168), each wave cycling one 8KB pair-slot 1-ahead.
    int blocks = 768;
    int nWaves = blocks * 4;
    if (nWaves > nPairs) { blocks = (nPairs + 3) / 4; nWaves = blocks * 4; }

    hipLaunchKernelGGL(coil_fused, dim3(blocks), dim3(256), 0, stream,
                       x, u, W1, b1, Wb, bb, out, nPairs, nWaves);
}

// Round 13
// 53.622 us; speedup vs baseline: 7.7185x; 1.1387x over previous
//
#include <hip/hip_runtime.h>
#include <stdint.h>

// Problem: B=1,000,000 rows; IN=64, H=128, OUT=2, 3 heads, per-row routing u in [0,3).
// out[b,:] = Wb[u[b]] @ relu(W1 @ x[b] + b1) + bb[u[b]]
//
// Roofline: mandatory HBM = x(256MB) + u(4MB) + out(8MB) ~ 268MB -> ~43us @ 6.3TB/s.
//
// Journal:
//  R2:  99us. LDS-W1, x global->reg, no prefetch. Latency-bound.
//  R3: 135us. Reg-prefetch + forced 64-VGPR cap -> spill. Cap was the bug.
//  R4: 343us. launch_bounds(256,8) -> VGPR 32 -> 225MB spill writes.
//  R5: 190us. waves_per_eu(4,4) -> allocator pinned 64, spilled. Attributes poison.
//  R6:  61us. Per-wave LDS ring + global_load_lds (bytes live in vmcnt queue). WIN.
//  R7:  53us. Pair-shared W1 reads + 1-ahead single-slot restage. CHAMPION.
//       ~5.0 TB/s effective (~80% of achievable); 12 waves/CU, LDS-bound residency.
//  R8:  56us. Quad slots halved waves/CU: concurrency > wait-distance.
//  R9: 414us. One global atomic per pair serialized all (~75M/s same-line atomics).
//  R10: 85us. Direct global->reg x prefetch loses to LDS-DMA staging.
//  R11: 69us. W1-in-regs from GLOBAL: 96MB prologue storm + VGPR pressure.
//  R12: 61us. W1-in-regs from LDS (clean test): +64 VGPR live set crossed the
//       168-reg/3-wave boundary -> TLP loss > LDS savings. FALSIFIED the LDS-op
//       theory; R7's in-loop W1 reads were already hidden.
//  R13 (this): REVERT to R7 byte-identical. Every single-variable neighbor of R7
//       (slot depth, scheduling, staging mechanism, W1 placement x2) has lost;
//       R7 is the empirical optimum of this design family at ~80% achievable BW.

typedef float f32x4 __attribute__((ext_vector_type(4)));
typedef int   i32x4 __attribute__((ext_vector_type(4)));
typedef short short8 __attribute__((ext_vector_type(8)));
typedef __bf16 bf16x8 __attribute__((ext_vector_type(8)));

#define GLOBAL_AS __attribute__((address_space(1)))
#define LDS_AS    __attribute__((address_space(3)))

static __device__ __forceinline__ f32x4 mfma16(bf16x8 a, bf16x8 b, f32x4 c) {
    return __builtin_amdgcn_mfma_f32_16x16x32_bf16(a, b, c, 0, 0, 0);
}

// MFMA k-packing: any bijection (gamma=lane>>4, j)->k works if A and B use the same one.
// Trunk (K=32 step s): k = 32s + 8g + j. D: col=lane&15=batch row, row = h-dim 16t+4g+r.
// Head: A2 row = batch row (matches trunk D -> zero cross-lane movement); k-bijection
//   n = 32s + 16*(j>>2) + 4g + (j&3) = exactly the h-dims this lane holds.
//   D2: col=lane&15 = head*2+out combo (<6), row -> batch row base+4g+r.
__global__ __launch_bounds__(256) void coil_fused(
    const float* __restrict__ x,
    const int*   __restrict__ u,    // routing ids, int32 on device
    const float* __restrict__ W1,   // [128][64]
    const float* __restrict__ b1,   // [128]
    const float* __restrict__ Wb,   // [3][2][128]
    const float* __restrict__ bb,   // [3][2]
    float* __restrict__ out,        // [B][2]
    int nPairs, int nWaves)
{
    __shared__ short w1s[128 * 64];   // 16 KB: W1 as bf16, XOR-swizzled rows
    __shared__ float b1s[128];
    __shared__ float xsl[4][2048];    // 32 KB: per-wave pair slot (8KB each)

    const int tid  = threadIdx.x;
    const int lane = tid & 63;
    const int c    = lane & 15;       // MFMA "parallel" index
    const int g    = lane >> 4;       // k-group gamma
    const int wsl  = tid >> 6;        // wave slot within block

    // ---- stage W1 into LDS as bf16, swizzled: phys = logical ^ ((row&7)<<4) ----
    for (int qq = tid; qq < 1024; qq += 256) {
        int row = qq >> 3;
        const float* src = W1 + row * 64 + (qq & 7) * 8;
        short8 v;
        #pragma unroll
        for (int j = 0; j < 8; ++j) v[j] = __builtin_bit_cast(short, (__bf16)src[j]);
        int phys = (qq * 16) ^ ((row & 7) << 4);
        *reinterpret_cast<short8*>(reinterpret_cast<char*>(w1s) + phys) = v;
    }
    if (tid < 128) b1s[tid] = b1[tid];

    // ---- loop-invariant head-weight fragments (16 VGPR) + head bias ----
    const int ko = c;                  // combo = head*2 + out_pos; valid if < 6
    const bool kvalid = (ko < 6);
    bf16x8 B2[4];
    #pragma unroll
    for (int s = 0; s < 4; ++s) {
        #pragma unroll
        for (int j = 0; j < 8; ++j) {
            int n = 32 * s + ((j >> 2) << 4) + 4 * g + (j & 3);
            B2[s][j] = kvalid ? (__bf16)Wb[ko * 128 + n] : (__bf16)0.0f;
        }
    }
    const float bbr = kvalid ? bb[ko] : 0.0f;
    const int khead = ko >> 1, opos = ko & 1;

    __syncthreads();   // only barrier in the kernel

    // ---- per-lane pre-swizzled GLOBAL offsets for x staging (8 chunks of 1KB) ----
    // LDS phys byte P = i*1024 + lane*16 holds x logical byte P ^ (((P>>8)&7)<<4)
    // (XOR touches bits 4-6 only; row bits unaffected).
    int xoff[8];
    #pragma unroll
    for (int i = 0; i < 8; ++i) {
        int pb = i * 1024 + lane * 16;
        xoff[i] = pb ^ (((pb >> 8) & 7) << 4);
    }

    // ---- x read offsets within the slot (bytes), swizzle-corrected; tile B = +4096 ----
    const int sw  = (c & 7) << 4;
    const int r00 = (c * 256 + g * 32 +   0) ^ sw;   // s=0, j=0..3
    const int r01 = (c * 256 + g * 32 +  16) ^ sw;   // s=0, j=4..7
    const int r10 = (c * 256 + g * 32 + 128) ^ sw;   // s=1, j=0..3
    const int r11 = (c * 256 + g * 32 + 144) ^ sw;   // s=1, j=4..7

    const char* xb8 = reinterpret_cast<const char*>(x);
    const char* w1b = reinterpret_cast<const char*>(w1s);
    float* slot = &xsl[wsl][0];
    LDS_AS char* dst = (LDS_AS char*)slot;
    const char* sb = reinterpret_cast<const char*>(slot);

    auto stage = [&](int pairIdx, i32x4& uvA, i32x4& uvB) {
        const int t0 = pairIdx * 2;
        uvA = *reinterpret_cast<const i32x4*>(u + t0 * 16 + 4 * g);
        uvB = *reinterpret_cast<const i32x4*>(u + t0 * 16 + 16 + 4 * g);
        const char* src = xb8 + (size_t)t0 * 4096;
        #pragma unroll
        for (int i = 0; i < 8; ++i)
            __builtin_amdgcn_global_load_lds((const GLOBAL_AS void*)(src + xoff[i]),
                                             (LDS_AS void*)(dst + i * 1024), 16, 0, 0);
    };

    // ---- contiguous pair chunk per wave ----
    const int w = blockIdx.x * 4 + wsl;
    const int qv = nPairs / nWaves, rm = nPairs % nWaves;
    int p          = w * qv + (w < rm ? w : rm);
    const int pend = p + qv + (w < rm ? 1 : 0);
    if (p >= pend) return;

    i32x4 uvA, uvB, nuvA, nuvB;
    stage(p, uvA, uvB);

    for (; p < pend; ++p) {
        // ---- read both tiles' x fragments (waits on this slot's in-flight DMA) ----
        f32x4 xaA = *reinterpret_cast<const f32x4*>(sb + r00);
        f32x4 xbA = *reinterpret_cast<const f32x4*>(sb + r01);
        f32x4 xcA = *reinterpret_cast<const f32x4*>(sb + r10);
        f32x4 xdA = *reinterpret_cast<const f32x4*>(sb + r11);
        f32x4 xaB = *reinterpret_cast<const f32x4*>(sb + 4096 + r00);
        f32x4 xbB = *reinterpret_cast<const f32x4*>(sb + 4096 + r01);
        f32x4 xcB = *reinterpret_cast<const f32x4*>(sb + 4096 + r10);
        f32x4 xdB = *reinterpret_cast<const f32x4*>(sb + 4096 + r11);

        // ensure the ds_reads above retired before the DMA below can overwrite the slot
        asm volatile("s_waitcnt lgkmcnt(0)" ::: "memory");

        // ---- refill slot with next pair (skip when out of chunk) ----
        if (p + 1 < pend) stage(p + 1, nuvA, nuvB);

        bf16x8 B1aA, B1bA, B1aB, B1bB;
        #pragma unroll
        for (int j = 0; j < 4; ++j) {
            B1aA[j] = (__bf16)xaA[j];  B1aA[4 + j] = (__bf16)xbA[j];
            B1bA[j] = (__bf16)xcA[j];  B1bA[4 + j] = (__bf16)xdA[j];
            B1aB[j] = (__bf16)xaB[j];  B1aB[4 + j] = (__bf16)xbB[j];
            B1bB[j] = (__bf16)xcB[j];  B1bB[4 + j] = (__bf16)xdB[j];
        }

        // ---- fused trunk+head, W1/b1 fragments shared by both tiles ----
        f32x4 oaccA = {0.f, 0.f, 0.f, 0.f};
        f32x4 oaccB = {0.f, 0.f, 0.f, 0.f};
        #pragma unroll
        for (int s = 0; s < 4; ++s) {
            const int t0 = 2 * s, t1 = 2 * s + 1;
            f32x4 bia0 = *reinterpret_cast<const f32x4*>(&b1s[16 * t0 + 4 * g]); // bcast
            f32x4 bia1 = *reinterpret_cast<const f32x4*>(&b1s[16 * t1 + 4 * g]);
            const int lo0 = (16 * t0 + c) * 128 + 16 * g;
            const int lo1 = (16 * t1 + c) * 128 + 16 * g;
            short8 A00 = *reinterpret_cast<const short8*>(w1b + (lo0 ^ sw));
            short8 A01 = *reinterpret_cast<const short8*>(w1b + ((lo0 + 64) ^ sw));
            short8 A10 = *reinterpret_cast<const short8*>(w1b + (lo1 ^ sw));
            short8 A11 = *reinterpret_cast<const short8*>(w1b + ((lo1 + 64) ^ sw));
            f32x4 h0A = bia0, h1A = bia1, h0B = bia0, h1B = bia1;
            h0A = mfma16(__builtin_bit_cast(bf16x8, A00), B1aA, h0A);
            h0B = mfma16(__builtin_bit_cast(bf16x8, A00), B1aB, h0B);
            h1A = mfma16(__builtin_bit_cast(bf16x8, A10), B1aA, h1A);
            h1B = mfma16(__builtin_bit_cast(bf16x8, A10), B1aB, h1B);
            h0A = mfma16(__builtin_bit_cast(bf16x8, A01), B1bA, h0A);
            h0B = mfma16(__builtin_bit_cast(bf16x8, A01), B1bB, h0B);
            h1A = mfma16(__builtin_bit_cast(bf16x8, A11), B1bA, h1A);
            h1B = mfma16(__builtin_bit_cast(bf16x8, A11), B1bB, h1B);
            bf16x8 A2A, A2B;
            #pragma unroll
            for (int j = 0; j < 4; ++j) {
                A2A[j]     = (__bf16)fmaxf(h0A[j], 0.0f);
                A2A[4 + j] = (__bf16)fmaxf(h1A[j], 0.0f);
                A2B[j]     = (__bf16)fmaxf(h0B[j], 0.0f);
                A2B[4 + j] = (__bf16)fmaxf(h1B[j], 0.0f);
            }
            oaccA = mfma16(A2A, B2[s], oaccA);
            oaccB = mfma16(A2B, B2[s], oaccB);
        }

        // ---- per-row head select + store (each out element hits exactly 1 lane) ----
        const int m0 = p * 32 + 4 * g;          // tile A rows; tile B rows = +16
        if (khead == uvA[0]) out[(m0 +  0) * 2 + opos] = oaccA[0] + bbr;
        if (khead == uvA[1]) out[(m0 +  1) * 2 + opos] = oaccA[1] + bbr;
        if (khead == uvA[2]) out[(m0 +  2) * 2 + opos] = oaccA[2] + bbr;
        if (khead == uvA[3]) out[(m0 +  3) * 2 + opos] = oaccA[3] + bbr;
        if (khead == uvB[0]) out[(m0 + 16) * 2 + opos] = oaccB[0] + bbr;
        if (khead == uvB[1]) out[(m0 + 17) * 2 + opos] = oaccB[1] + bbr;
        if (khead == uvB[2]) out[(m0 + 18) * 2 + opos] = oaccB[2] + bbr;
        if (khead == uvB[3]) out[(m0 + 19) * 2 + opos] = oaccB[3] + bbr;

        uvA = nuvA; uvB = nuvB;
    }
}

extern "C" void kernel_launch(void* const* d_in, const int* in_sizes, int n_in,
                              void* d_out, int out_size, void* d_ws, size_t ws_size,
                              hipStream_t stream) {
    const float* x  = (const float*)d_in[0];
    const int*   u  = (const int*)d_in[1];   // integer inputs are int32 on device
    const float* W1 = (const float*)d_in[2];
    const float* b1 = (const float*)d_in[3];
    const float* Wb = (const float*)d_in[4];
    const float* bb = (const float*)d_in[5];
    float* out = (float*)d_out;

    const int B = in_sizes[1];        // u has one element per row
    const int nTiles = B / 16;        // 62,500 (exact)
    const int nPairs = nTiles / 2;    // 31,250 (exact)

    // LDS/block = 48.5KB -> 3 blocks/CU -> 768 blocks all co-resident (12 waves/CU),
    // each wave cycling one 8KB pair-slot staged one pair ahead.
    int blocks = 768;
    int nWaves = blocks * 4;
    if (nWaves > nPairs) { blocks = (nPairs + 3) / 4; nWaves = blocks * 4; }

    hipLaunchKernelGGL(coil_fused, dim3(blocks), dim3(256), 0, stream,
                       x, u, W1, b1, Wb, bb, out, nPairs, nWaves);
}